// Round 1
// baseline (10.444 us; speedup 1.0000x reference)
//
#include <hip/hip_runtime.h>

// out layout: [ out (B,16) | carry (B,16) ] floats, concatenated.
// One thread per (b,k), t = b*4 + k. Groups of 4 lanes share one row b.
__global__ __launch_bounds__(256) void sga_kernel(const float* __restrict__ x,
                                                  float* __restrict__ out,
                                                  int BK) {
    int t = blockIdx.x * blockDim.x + threadIdx.x;
    if (t >= BK) return;

    // 64B contiguous per thread: 4 x float4
    const float4* xp = reinterpret_cast<const float4*>(x) + (size_t)t * 4;
    float4 v0 = xp[0], v1 = xp[1], v2 = xp[2], v3 = xp[3];

    unsigned a = 0;
    a |= (unsigned)(v0.x != 0.0f) << 0;
    a |= (unsigned)(v0.y != 0.0f) << 1;
    a |= (unsigned)(v0.z != 0.0f) << 2;
    a |= (unsigned)(v0.w != 0.0f) << 3;
    a |= (unsigned)(v1.x != 0.0f) << 4;
    a |= (unsigned)(v1.y != 0.0f) << 5;
    a |= (unsigned)(v1.z != 0.0f) << 6;
    a |= (unsigned)(v1.w != 0.0f) << 7;
    a |= (unsigned)(v2.x != 0.0f) << 8;
    a |= (unsigned)(v2.y != 0.0f) << 9;
    a |= (unsigned)(v2.z != 0.0f) << 10;
    a |= (unsigned)(v2.w != 0.0f) << 11;
    a |= (unsigned)(v3.x != 0.0f) << 12;
    a |= (unsigned)(v3.y != 0.0f) << 13;
    a |= (unsigned)(v3.z != 0.0f) << 14;
    a |= (unsigned)(v3.w != 0.0f) << 15;

    // group-of-4 total (xor-1 and xor-2 stay within the 4-lane group)
    unsigned tot = a + __shfl_xor(a, 1);
    tot += __shfl_xor(tot, 2);
    unsigned bb = (tot - a) & 0xFFFFu;   // residual bits 0..15 (matches ref mask)

    unsigned sum = a + bb;               // <= 131070, 17 bits
    unsigned s   = sum & 0xFFFFu;        // sum bits
    unsigned cin = a ^ bb ^ s;           // carry-in bits (bit0 == 0)
    unsigned c   = (cin >> 1) | (((sum >> 16) & 1u) << 15);  // carry-out bits

    // spread 8 bits -> 8 nibbles of a u32
    auto spread8 = [](unsigned b) {
        unsigned u = (b | (b << 12)) & 0x000F000Fu;
        u = (u | (u << 6)) & 0x03030303u;
        u = (u | (u << 3)) & 0x11111111u;
        return u;
    };
    unsigned long long ss = (unsigned long long)spread8(s & 0xFFu) |
                            ((unsigned long long)spread8((s >> 8) & 0xFFu) << 32);
    unsigned long long cc = (unsigned long long)spread8(c & 0xFFu) |
                            ((unsigned long long)spread8((c >> 8) & 0xFFu) << 32);

    // per-bit sums over the 4 lanes of the group (each nibble <= 4)
    ss += __shfl_xor(ss, 1); ss += __shfl_xor(ss, 2);
    cc += __shfl_xor(cc, 1); cc += __shfl_xor(cc, 2);

    // lane k of the group writes bit positions 4k..4k+3 for row b:
    // global float offset = b*16 + k*4 = 4t  -> coalesced float4 stores
    int sh = (t & 3) * 16;
    float4 o, ca;
    o.x  = (float)((ss >> (sh + 0))  & 0xFULL) * 0.25f;
    o.y  = (float)((ss >> (sh + 4))  & 0xFULL) * 0.25f;
    o.z  = (float)((ss >> (sh + 8))  & 0xFULL) * 0.25f;
    o.w  = (float)((ss >> (sh + 12)) & 0xFULL) * 0.25f;
    ca.x = (float)((cc >> (sh + 0))  & 0xFULL);
    ca.y = (float)((cc >> (sh + 4))  & 0xFULL);
    ca.z = (float)((cc >> (sh + 8))  & 0xFULL);
    ca.w = (float)((cc >> (sh + 12)) & 0xFULL);

    float4* outv = reinterpret_cast<float4*>(out);
    outv[t]      = o;          // out   region: float4 index t
    outv[BK + t] = ca;         // carry region starts at float BK*4 == float4 BK
}

extern "C" void kernel_launch(void* const* d_in, const int* in_sizes, int n_in,
                              void* d_out, int out_size, void* d_ws, size_t ws_size,
                              hipStream_t stream) {
    const float* x = (const float*)d_in[0];   // (B, K=4, 16) f32 in {0,1}
    // d_in[1] (p) is unused by the reference — intentionally not read.
    float* out = (float*)d_out;
    int BK = in_sizes[0] / 16;                // B*K = 262144
    int threads = 256;
    int blocks = (BK + threads - 1) / threads;
    sga_kernel<<<blocks, threads, 0, stream>>>(x, out, BK);
}